// Round 10
// baseline (397.644 us; speedup 1.0000x reference)
//
#include <hip/hip_runtime.h>

typedef unsigned short u16;
typedef u16 ushort8 __attribute__((ext_vector_type(8)));
typedef u16 ushort4v __attribute__((ext_vector_type(4)));
typedef __bf16 bf16x8 __attribute__((ext_vector_type(8)));
typedef float f32x4 __attribute__((ext_vector_type(4)));

#define PI_F 3.14159265358979323846f

__device__ __forceinline__ u16 f2bf(float f) {
  union { float f; unsigned int u; } v; v.f = f;
  unsigned int r = v.u + 0x7fffu + ((v.u >> 16) & 1u);
  return (u16)(r >> 16);
}
__device__ __forceinline__ float bf2f(u16 u) {
  union { unsigned int u; float f; } v; v.u = ((unsigned int)u) << 16;
  return v.f;
}

// async global->LDS, 16B per lane; LDS dest = wave-uniform base + lane*16
__device__ __forceinline__ void gload16(const u16* g, u16* l) {
  __builtin_amdgcn_global_load_lds((const __attribute__((address_space(1))) void*)g,
                                   (__attribute__((address_space(3))) void*)l, 16, 0, 0);
}

// stage a 128x32 bf16 tile into linear LDS [128][32]  (helper for 128^2 GEMMs)
__device__ __forceinline__ void stage_tile(const u16* __restrict__ G, int ld, int row0, int k0,
                                           u16* lds, int wid, int lane) {
  int seg = wid * 32;
  const u16* gp = G + (size_t)(row0 + seg + (lane >> 2)) * ld + k0 + (lane & 3) * 8;
  gload16(gp, lds + seg * 32);
  gload16(gp + (size_t)16 * ld, lds + (seg + 16) * 32);
}

#define WAIT_VM(N) asm volatile("s_waitcnt vmcnt(" #N ")" ::: "memory")
#define RAW_BARRIER() asm volatile("s_barrier" ::: "memory")

// local 32x32 tables
__device__ __forceinline__ float im_val(int r, int c) {
  float xy = (float)(r > c ? r : c);
  float m = (xy <= 3.0f) ? (1.0f - xy * (0.95f / 3.0f))
           : ((xy <= 22.0f) ? 0.01f : ((xy - 22.0f) * 0.03f));
  return 1.0f - m;
}
__device__ __forceinline__ float dct_val(int r, int c) {
  int a = ((2 * c + 1) * r) & 127;
  float s = (r == 0) ? 0.17677669529663687f : 0.25f;
  return cosf((float)a * (PI_F / 64.0f)) * s;
}

// ---------------- masked-DCT adjoint of one 1024-row (32x32 image) ----------------
__device__ void mdct_row(const float* __restrict__ row, u16* __restrict__ dst, float* sm, int t) {
  float* Ms = sm; float* T1 = sm + 1056; float* Dsh = sm + 2112;
  for (int i = t; i < 1024; i += 256) {
    int r = i >> 5, c = i & 31;
    Dsh[r * 33 + c] = dct_val(r, c);
    Ms[r * 33 + c] = row[i] * im_val(r, c);
  }
  __syncthreads();
  int k = t >> 3, l0 = (t & 7) * 4;
  float a0 = 0, a1 = 0, a2 = 0, a3 = 0;
  #pragma unroll 8
  for (int i = 0; i < 32; ++i) {
    float d = Dsh[i * 33 + k];
    const float* mr = &Ms[i * 33 + l0];
    a0 += d * mr[0]; a1 += d * mr[1]; a2 += d * mr[2]; a3 += d * mr[3];
  }
  T1[k * 33 + l0 + 0] = a0; T1[k * 33 + l0 + 1] = a1;
  T1[k * 33 + l0 + 2] = a2; T1[k * 33 + l0 + 3] = a3;
  __syncthreads();
  float b0 = 0, b1 = 0, b2 = 0, b3 = 0;
  #pragma unroll 8
  for (int j = 0; j < 32; ++j) {
    float u = T1[k * 33 + j];
    b0 += u * Dsh[j * 33 + l0 + 0];
    b1 += u * Dsh[j * 33 + l0 + 1];
    b2 += u * Dsh[j * 33 + l0 + 2];
    b3 += u * Dsh[j * 33 + l0 + 3];
  }
  ushort4v o;
  o[0] = f2bf(b0); o[1] = f2bf(b1); o[2] = f2bf(b2); o[3] = f2bf(b3);
  *(ushort4v*)(dst + k * 32 + l0) = o;
}

// ---- stage1: prep(0..2047) + weff(2048..2303) + beff(2304) + tok2(2305..2432) + t2f(2433..2560)
__global__ __launch_bounds__(256) void k_stage1(const float* __restrict__ feats,
                                                const float* __restrict__ lt, const int* __restrict__ layerp,
                                                const float* __restrict__ Wt2f, const float* __restrict__ bt2f,
                                                const float* __restrict__ Wdf, const float* __restrict__ bdf,
                                                u16* __restrict__ xb, u16* __restrict__ A2,
                                                float* __restrict__ outp,
                                                float* __restrict__ weff_f, u16* __restrict__ weff_bf,
                                                float* __restrict__ beff, u16* __restrict__ tok2,
                                                u16* __restrict__ t2f) {
  __shared__ __align__(16) float sm[14784];
  int bid = blockIdx.x, t = threadIdx.x;
  if (bid < 2048) {
    int tid = bid * 256 + t;   // 524288 total
    const float4* in4 = (const float4*)(feats + 32768);
    ushort4v* xb4 = (ushort4v*)xb;
    #pragma unroll
    for (int rep = 0; rep < 16; ++rep) {
      int j = tid + rep * 524288;
      float4 v = in4[j];
      ushort4v o;
      o[0] = f2bf(v.x); o[1] = f2bf(v.y); o[2] = f2bf(v.z); o[3] = f2bf(v.w);
      xb4[j] = o;
    }
    ((ushort8*)A2)[tid] = (ushort8){0,0,0,0,0,0,0,0};
    if (tid < 32768) outp[tid] = feats[tid];
    return;
  }
  int b2 = bid - 2048;
  if (b2 < 256) {
    float* In = sm; float* Uc = sm + 4224; float* Us = sm + 8448;
    float* Csh = sm + 12672; float* Ssh = sm + 13728;
    int c0 = b2 * 4;
    for (int i = t; i < 1024; i += 256) {
      int r = i >> 5, c = i & 31;
      float ang = (float)((r * c) & 31) * (PI_F / 16.0f);
      Csh[r * 33 + c] = cosf(ang); Ssh[r * 33 + c] = sinf(ang);
    }
    { int cc = t & 3, v0 = t >> 2;
      for (int v = v0; v < 1024; v += 64)
        In[cc * 1056 + (v >> 5) * 33 + (v & 31)] = Wdf[(size_t)v * 1024 + c0 + cc]; }
    __syncthreads();
    int cc = t >> 6, L2 = t & 63, p = L2 & 31, h = L2 >> 5;
    for (int j = h * 16; j < h * 16 + 16; ++j) {
      float ac = 0, as = 0;
      #pragma unroll 8
      for (int i = 0; i < 32; ++i) {
        float m = In[cc * 1056 + i * 33 + j];
        ac += Csh[p * 33 + i] * m;
        as += Ssh[p * 33 + i] * m;
      }
      Uc[cc * 1056 + p * 33 + j] = ac;
      Us[cc * 1056 + p * 33 + j] = as;
    }
    __syncthreads();
    for (int q = h * 16; q < h * 16 + 16; ++q) {
      float acc = 0;
      #pragma unroll 8
      for (int j = 0; j < 32; ++j)
        acc += Uc[cc * 1056 + p * 33 + j] * Csh[q * 33 + j] -
               Us[cc * 1056 + p * 33 + j] * Ssh[q * 33 + j];
      float val = acc * 0.03125f;
      size_t idx = (size_t)(p * 32 + q) * 1024 + c0 + cc;
      weff_f[idx] = val;
      weff_bf[idx] = f2bf(val);
    }
  } else if (b2 == 256) {
    float* Bsh = sm; float* Uc = sm + 1056; float* Us = sm + 2112;
    float* Csh = sm + 3168; float* Ssh = sm + 4224;
    for (int i = t; i < 1024; i += 256) {
      int r = i >> 5, c = i & 31;
      float ang = (float)((r * c) & 31) * (PI_F / 16.0f);
      Csh[r * 33 + c] = cosf(ang); Ssh[r * 33 + c] = sinf(ang);
      Bsh[r * 33 + c] = bdf[i];
    }
    __syncthreads();
    for (int idx = t; idx < 1024; idx += 256) {
      int p = idx >> 5, j = idx & 31;
      float ac = 0, as = 0;
      #pragma unroll 8
      for (int i = 0; i < 32; ++i) {
        float m = Bsh[i * 33 + j];
        ac += Csh[p * 33 + i] * m;
        as += Ssh[p * 33 + i] * m;
      }
      Uc[p * 33 + j] = ac; Us[p * 33 + j] = as;
    }
    __syncthreads();
    for (int idx = t; idx < 1024; idx += 256) {
      int p = idx >> 5, q = idx & 31;
      float acc = 0;
      #pragma unroll 8
      for (int jj = 0; jj < 32; ++jj)
        acc += Uc[p * 33 + jj] * Csh[q * 33 + jj] - Us[p * 33 + jj] * Ssh[q * 33 + jj];
      beff[idx] = acc * 0.03125f;
    }
  } else if (b2 < 385) {
    int p = b2 - 257;   // 0..127
    if (p >= 100) {
      *(ushort4v*)(tok2 + (size_t)p * 1024 + t * 4) = (ushort4v){0,0,0,0};
      return;
    }
    mdct_row(lt + (size_t)(*layerp) * 102400 + (size_t)p * 1024, tok2 + (size_t)p * 1024, sm, t);
  } else {
    // t2f row m: t2f[m] = tokens[m+1] @ W_t2f^T + b  (f32 math, bf16 store)
    int m = b2 - 385;   // 0..127
    if (m >= 99) {
      for (int c = t; c < 1024; c += 256) t2f[(size_t)m * 1024 + c] = 0;
      return;
    }
    float* tokrow = sm;
    int L = *layerp;
    const float* tr = lt + (size_t)L * 102400 + (size_t)(m + 1) * 1024;
    for (int i = t; i < 1024; i += 256) tokrow[i] = tr[i];
    __syncthreads();
    for (int c = t; c < 1024; c += 256) {
      const float4* w4 = (const float4*)(Wt2f + (size_t)c * 1024);
      float acc = 0;
      #pragma unroll 4
      for (int k = 0; k < 256; k++) {
        float4 w = w4[k];
        acc += tokrow[4 * k + 0] * w.x + tokrow[4 * k + 1] * w.y +
               tokrow[4 * k + 2] * w.z + tokrow[4 * k + 3] * w.w;
      }
      t2f[(size_t)m * 1024 + c] = f2bf(acc + bt2f[c]);
    }
  }
}

// ---------------- 128x128 ring-buffer GEMM core (NT K-tiles of 32), counted vmcnt ------
template <int NT>
__device__ __forceinline__ void gemm128_core(const u16* __restrict__ A, int lda,
                                             const u16* __restrict__ B, int ldb,
                                             int g0, int c0, u16* smem,
                                             f32x4 (&acc)[4][4], int wid, int lane) {
  int wr = wid >> 1, wc = wid & 1, cl = lane & 15, rg = lane >> 4;
  stage_tile(A, lda, g0, 0, smem, wid, lane);
  stage_tile(B, ldb, c0, 0, smem + 12288, wid, lane);
  stage_tile(A, lda, g0, 32, smem + 4096, wid, lane);
  stage_tile(B, ldb, c0, 32, smem + 16384, wid, lane);
  int cur = 0;
  #pragma unroll 1
  for (int kt = 0; kt < NT; ++kt) {
    if (kt == NT - 1) { WAIT_VM(0); } else { WAIT_VM(4); }
    RAW_BARRIER();
    if (kt + 2 < NT) {
      int slot = (cur == 0) ? 2 : cur - 1;
      stage_tile(A, lda, g0, (kt + 2) * 32, smem + slot * 4096, wid, lane);
      stage_tile(B, ldb, c0, (kt + 2) * 32, smem + 12288 + slot * 4096, wid, lane);
    }
    const u16* pa = smem + cur * 4096;
    const u16* pb = smem + 12288 + cur * 4096;
    bf16x8 af[4], bv[4];
    #pragma unroll
    for (int mf = 0; mf < 4; mf++)
      af[mf] = *(const bf16x8*)(pa + (wr * 64 + mf * 16 + cl) * 32 + rg * 8);
    #pragma unroll
    for (int nf = 0; nf < 4; nf++)
      bv[nf] = *(const bf16x8*)(pb + (wc * 64 + nf * 16 + cl) * 32 + rg * 8);
    #pragma unroll
    for (int mf = 0; mf < 4; mf++)
      #pragma unroll
      for (int nf = 0; nf < 4; nf++)
        acc[mf][nf] = __builtin_amdgcn_mfma_f32_16x16x32_bf16(af[mf], bv[nf], acc[mf][nf], 0, 0, 0);
    cur = (cur == 2) ? 0 : cur + 1;
  }
}

// ---------------- stage2: Gt (0..7) + attn (8..263) + w2 mdct (264..1287) ----------------
__global__ __launch_bounds__(256) void k_stage2(const float* __restrict__ weff_f,
                                                const u16* __restrict__ weff_bf, const u16* __restrict__ t2f,
                                                const u16* __restrict__ xb, const u16* __restrict__ tok2,
                                                u16* __restrict__ w2, u16* __restrict__ Gt,
                                                u16* __restrict__ A2) {
  __shared__ __align__(16) u16 smem[24576];
  int bid = blockIdx.x, t = threadIdx.x;
  int lane = t & 63, wid = t >> 6;
  if (bid < 8) {
    int wr = wid >> 1, wc = wid & 1, cl = lane & 15, rg = lane >> 4;
    f32x4 acc[4][4];
    #pragma unroll
    for (int i = 0; i < 4; i++)
      #pragma unroll
      for (int j = 0; j < 4; j++) acc[i][j] = (f32x4){0.f,0.f,0.f,0.f};
    gemm128_core<32>(weff_bf, 1024, t2f, 1024, bid * 128, 0, smem, acc, wid, lane);
    #pragma unroll
    for (int mf = 0; mf < 4; mf++)
      #pragma unroll
      for (int nf = 0; nf < 4; nf++) {
        int col = wc * 64 + nf * 16 + cl;
        #pragma unroll
        for (int r = 0; r < 4; r++) {
          int row = bid * 128 + wr * 64 + mf * 16 + rg * 4 + r;
          Gt[(size_t)row * 128 + col] = f2bf(acc[mf][nf][r]);
        }
      }
  } else if (bid < 264) {
    int g0 = (bid - 8) * 128;
    int cl = lane & 15, rg = lane >> 4;
    f32x4 acc[2][7];
    #pragma unroll
    for (int i = 0; i < 2; i++)
      #pragma unroll
      for (int j = 0; j < 7; j++) acc[i][j] = (f32x4){0.f,0.f,0.f,0.f};
    stage_tile(xb, 1024, g0, 0, smem, wid, lane);
    stage_tile(tok2, 1024, 0, 0, smem + 12288, wid, lane);
    stage_tile(xb, 1024, g0, 32, smem + 4096, wid, lane);
    stage_tile(tok2, 1024, 0, 32, smem + 16384, wid, lane);
    int cur = 0;
    #pragma unroll 1
    for (int kt = 0; kt < 32; ++kt) {
      if (kt == 31) { WAIT_VM(0); } else { WAIT_VM(4); }
      RAW_BARRIER();
      if (kt + 2 < 32) {
        int slot = (cur == 0) ? 2 : cur - 1;
        stage_tile(xb, 1024, g0, (kt + 2) * 32, smem + slot * 4096, wid, lane);
        stage_tile(tok2, 1024, 0, (kt + 2) * 32, smem + 12288 + slot * 4096, wid, lane);
      }
      const u16* pa = smem + cur * 4096;
      const u16* pb = smem + 12288 + cur * 4096;
      bf16x8 a0 = *(const bf16x8*)(pa + (wid * 32 + cl) * 32 + rg * 8);
      bf16x8 a1 = *(const bf16x8*)(pa + (wid * 32 + 16 + cl) * 32 + rg * 8);
      #pragma unroll
      for (int nf = 0; nf < 7; nf++) {
        bf16x8 bv = *(const bf16x8*)(pb + (nf * 16 + cl) * 32 + rg * 8);
        acc[0][nf] = __builtin_amdgcn_mfma_f32_16x16x32_bf16(a0, bv, acc[0][nf], 0, 0, 0);
        acc[1][nf] = __builtin_amdgcn_mfma_f32_16x16x32_bf16(a1, bv, acc[1][nf], 0, 0, 0);
      }
      cur = (cur == 2) ? 0 : cur + 1;
    }
    #pragma unroll
    for (int mf = 0; mf < 2; mf++) {
      #pragma unroll
      for (int r = 0; r < 4; r++) {
        int grow = g0 + wid * 32 + mf * 16 + rg * 4 + r;
        float v[7];
        float mx = -1e30f;
        #pragma unroll
        for (int nf = 0; nf < 7; nf++) {
          int m = nf * 16 + cl;
          v[nf] = acc[mf][nf][r] * 0.03125f;
          if (m < 100) mx = fmaxf(mx, v[nf]);
        }
        #pragma unroll
        for (int d = 1; d < 16; d <<= 1) mx = fmaxf(mx, __shfl_xor(mx, d));
        float s = 0;
        #pragma unroll
        for (int nf = 0; nf < 7; nf++) {
          int m = nf * 16 + cl;
          float e = (m < 100) ? __expf(v[nf] - mx) : 0.0f;
          v[nf] = e; s += e;
        }
        #pragma unroll
        for (int d = 1; d < 16; d <<= 1) s += __shfl_xor(s, d);
        float inv = 1.0f / s;
        #pragma unroll
        for (int nf = 0; nf < 7; nf++) {
          int m = nf * 16 + cl;
          if (m >= 1 && m < 100) A2[(size_t)grow * 128 + (m - 1)] = f2bf(v[nf] * inv);
        }
      }
    }
  } else {
    mdct_row(weff_f + (size_t)(bid - 264) * 1024, w2 + (size_t)(bid - 264) * 1024, (float*)smem, t);
  }
}

// ---------------- main fused GEMM, 256x256 tile, 8 waves, BK=32, 2-slot dbuf (64 KB LDS,
// 2 blocks/CU -> cross-block latency hiding). out = x + clip([xb|A2]@[w2|Gt]^T + beff)*scale
__global__ __launch_bounds__(512, 2) void k_main(const u16* __restrict__ xb, const u16* __restrict__ w2,
                                                 const u16* __restrict__ a2, const u16* __restrict__ gt,
                                                 const float* __restrict__ beff, const float* __restrict__ feats,
                                                 const float* __restrict__ scalep, float* __restrict__ outf) {
  __shared__ __align__(16) u16 smem[32768];   // 64 KB: A slots 0/8192, B slots 16384/24576
  int tid = threadIdx.x, lane = tid & 63, wid = tid >> 6;
  int wr = wid >> 2, wc = wid & 3;            // 2 x 4 wave grid; wave tile 128x64
  int cl = lane & 15, rg = lane >> 4;
  int bid = blockIdx.x;
  int swz = (bid & 7) * 64 + (bid >> 3);      // XCD-chunked bijective swizzle (512 = 8*64)
  int bm = swz >> 2, bn = swz & 3;
  int g0 = bm * 256, c0 = bn * 256;

  f32x4 acc[8][4];
  #pragma unroll
  for (int i = 0; i < 8; i++)
    #pragma unroll
    for (int j = 0; j < 4; j++) acc[i][j] = (f32x4){0.f,0.f,0.f,0.f};

  const int NT = 36;   // K = 1152 = 36 x 32

  // precomputed swizzled fragment offsets (u16 units), statically indexed
  int offA[8], offB[4];
  #pragma unroll
  for (int mf = 0; mf < 8; ++mf) {
    int r = wr * 128 + mf * 16 + cl;
    int lrow = r >> 1;
    offA[mf] = lrow * 64 + (((((r & 1) << 2) | rg) ^ (lrow & 7)) << 3);
  }
  #pragma unroll
  for (int nf = 0; nf < 4; ++nf) {
    int r = wc * 64 + nf * 16 + cl;
    int lrow = r >> 1;
    offB[nf] = lrow * 64 + (((((r & 1) << 2) | rg) ^ (lrow & 7)) << 3);
  }

  auto issueA = [&](int t) {
    u16* R = smem + (t & 1) * 8192;
    const u16* G = (t < 32) ? xb : a2;
    int ld = (t < 32) ? 1024 : 128;
    int k0 = (t < 32) ? t * 32 : (t - 32) * 32;
    #pragma unroll
    for (int p = 0; p < 2; ++p) {
      int lrow = p * 64 + wid * 8 + (lane >> 3);
      int c2 = (lane & 7) ^ (lrow & 7);
      const u16* src = G + (size_t)(g0 + 2 * lrow + (c2 >> 2)) * ld + k0 + (c2 & 3) * 8;
      gload16(src, R + (p * 64 + wid * 8) * 64);
    }
  };
  auto issueB = [&](int t) {
    u16* R = smem + 16384 + (t & 1) * 8192;
    const u16* G = (t < 32) ? w2 : gt;
    int ld = (t < 32) ? 1024 : 128;
    int k0 = (t < 32) ? t * 32 : (t - 32) * 32;
    #pragma unroll
    for (int p = 0; p < 2; ++p) {
      int lrow = p * 64 + wid * 8 + (lane >> 3);
      int c2 = (lane & 7) ^ (lrow & 7);
      const u16* src = G + (size_t)(c0 + 2 * lrow + (c2 >> 2)) * ld + k0 + (c2 & 3) * 8;
      gload16(src, R + (p * 64 + wid * 8) * 64);
    }
  };

  issueA(0); issueB(0);   // prologue: 4 vm ops

  #pragma unroll 1
  for (int t = 0; t < NT; ++t) {
    WAIT_VM(0);            // tile-t loads landed (cross-block overlap hides this)
    RAW_BARRIER();
    if (t + 1 < NT) { issueA(t + 1); issueB(t + 1); }   // slot (t+1)&1: consumed at t-1
    int slot = t & 1;
    const u16* pa = smem + slot * 8192;
    const u16* pb = smem + 16384 + slot * 8192;
    bf16x8 af[8], bv[4];
    #pragma unroll
    for (int nf = 0; nf < 4; ++nf) bv[nf] = *(const bf16x8*)(pb + offB[nf]);
    #pragma unroll
    for (int mf = 0; mf < 8; ++mf) af[mf] = *(const bf16x8*)(pa + offA[mf]);
    __builtin_amdgcn_s_setprio(1);
    #pragma unroll
    for (int mf = 0; mf < 8; ++mf)
      #pragma unroll
      for (int nf = 0; nf < 4; ++nf)
        acc[mf][nf] = __builtin_amdgcn_mfma_f32_16x16x32_bf16(af[mf], bv[nf], acc[mf][nf], 0, 0, 0);
    __builtin_amdgcn_s_setprio(0);
  }

  float sc = *scalep;
  #pragma unroll
  for (int mf = 0; mf < 8; mf++) {
    #pragma unroll
    for (int nf = 0; nf < 4; nf++) {
      int col = c0 + wc * 64 + nf * 16 + cl;
      #pragma unroll
      for (int r = 0; r < 4; r++) {
        int row = g0 + wr * 128 + mf * 16 + rg * 4 + r;
        size_t idx = (size_t)row * 1024 + col;
        float val = acc[mf][nf][r] + beff[col];
        float rr = fminf(fmaxf(val, 0.f), 255.f);
        outf[32768 + idx] = feats[32768 + idx] + rr * sc;
      }
    }
  }
}

extern "C" void kernel_launch(void* const* d_in, const int* in_sizes, int n_in,
                              void* d_out, int out_size, void* d_ws, size_t ws_size,
                              hipStream_t stream) {
  const float* feats  = (const float*)d_in[0];
  const int*   layerp = (const int*)d_in[1];
  const float* lt     = (const float*)d_in[2];
  const float* scalep = (const float*)d_in[3];
  const float* Wt2f   = (const float*)d_in[4];
  const float* bt2f   = (const float*)d_in[5];
  const float* Wdf    = (const float*)d_in[6];
  const float* bdf    = (const float*)d_in[7];
  float* outp = (float*)d_out;

  char* ws = (char*)d_ws;
  float* beff   = (float*)(ws + 0);           // 4KB
  float* weff_f = (float*)(ws + 65536);       // 4MB
  u16* weff_bf = (u16*)(ws + 4259840);        // 2MB
  u16* w2      = (u16*)(ws + 6356992);        // 2MB
  u16* tok2    = (u16*)(ws + 10813440);       // 256KB
  u16* t2f     = (u16*)(ws + 11075584);       // 256KB
  u16* Gt      = (u16*)(ws + 11337728);       // 256KB (1024x128)
  u16* A2      = (u16*)(ws + 11599872);       // 8MB (32768x128)
  u16* xb      = (u16*)(ws + 19988480);       // 64MB (32768x1024)

  k_stage1<<<2561, 256, 0, stream>>>(feats, lt, layerp, Wt2f, bt2f, Wdf, bdf,
                                     xb, A2, outp, weff_f, weff_bf, beff, tok2, t2f);
  k_stage2<<<1288, 256, 0, stream>>>(weff_f, weff_bf, t2f, xb, tok2, w2, Gt, A2);
  k_main<<<512, 512, 0, stream>>>(xb, w2, A2, Gt, beff, feats, scalep, outp);
}

// Round 11
// 220.968 us; speedup vs baseline: 1.7996x; 1.7996x over previous
//
#include <hip/hip_runtime.h>

typedef unsigned short u16;
typedef u16 ushort8 __attribute__((ext_vector_type(8)));
typedef u16 ushort4v __attribute__((ext_vector_type(4)));
typedef __bf16 bf16x8 __attribute__((ext_vector_type(8)));
typedef float f32x4 __attribute__((ext_vector_type(4)));

#define PI_F 3.14159265358979323846f

__device__ __forceinline__ u16 f2bf(float f) {
  union { float f; unsigned int u; } v; v.f = f;
  unsigned int r = v.u + 0x7fffu + ((v.u >> 16) & 1u);
  return (u16)(r >> 16);
}
__device__ __forceinline__ float bf2f(u16 u) {
  union { unsigned int u; float f; } v; v.u = ((unsigned int)u) << 16;
  return v.f;
}

// async global->LDS, 16B per lane; LDS dest = wave-uniform base + lane*16
__device__ __forceinline__ void gload16(const u16* g, u16* l) {
  __builtin_amdgcn_global_load_lds((const __attribute__((address_space(1))) void*)g,
                                   (__attribute__((address_space(3))) void*)l, 16, 0, 0);
}

// stage a 128x32 bf16 tile into linear LDS [128][32]  (helper for 128^2 GEMMs)
__device__ __forceinline__ void stage_tile(const u16* __restrict__ G, int ld, int row0, int k0,
                                           u16* lds, int wid, int lane) {
  int seg = wid * 32;
  const u16* gp = G + (size_t)(row0 + seg + (lane >> 2)) * ld + k0 + (lane & 3) * 8;
  gload16(gp, lds + seg * 32);
  gload16(gp + (size_t)16 * ld, lds + (seg + 16) * 32);
}

#define WAIT_VM(N) asm volatile("s_waitcnt vmcnt(" #N ")" ::: "memory")
#define RAW_BARRIER() asm volatile("s_barrier" ::: "memory")

// local 32x32 tables
__device__ __forceinline__ float im_val(int r, int c) {
  float xy = (float)(r > c ? r : c);
  float m = (xy <= 3.0f) ? (1.0f - xy * (0.95f / 3.0f))
           : ((xy <= 22.0f) ? 0.01f : ((xy - 22.0f) * 0.03f));
  return 1.0f - m;
}
__device__ __forceinline__ float dct_val(int r, int c) {
  int a = ((2 * c + 1) * r) & 127;
  float s = (r == 0) ? 0.17677669529663687f : 0.25f;
  return cosf((float)a * (PI_F / 64.0f)) * s;
}

// ---------------- masked-DCT adjoint of one 1024-row (32x32 image) ----------------
__device__ void mdct_row(const float* __restrict__ row, u16* __restrict__ dst, float* sm, int t) {
  float* Ms = sm; float* T1 = sm + 1056; float* Dsh = sm + 2112;
  for (int i = t; i < 1024; i += 256) {
    int r = i >> 5, c = i & 31;
    Dsh[r * 33 + c] = dct_val(r, c);
    Ms[r * 33 + c] = row[i] * im_val(r, c);
  }
  __syncthreads();
  int k = t >> 3, l0 = (t & 7) * 4;
  float a0 = 0, a1 = 0, a2 = 0, a3 = 0;
  #pragma unroll 8
  for (int i = 0; i < 32; ++i) {
    float d = Dsh[i * 33 + k];
    const float* mr = &Ms[i * 33 + l0];
    a0 += d * mr[0]; a1 += d * mr[1]; a2 += d * mr[2]; a3 += d * mr[3];
  }
  T1[k * 33 + l0 + 0] = a0; T1[k * 33 + l0 + 1] = a1;
  T1[k * 33 + l0 + 2] = a2; T1[k * 33 + l0 + 3] = a3;
  __syncthreads();
  float b0 = 0, b1 = 0, b2 = 0, b3 = 0;
  #pragma unroll 8
  for (int j = 0; j < 32; ++j) {
    float u = T1[k * 33 + j];
    b0 += u * Dsh[j * 33 + l0 + 0];
    b1 += u * Dsh[j * 33 + l0 + 1];
    b2 += u * Dsh[j * 33 + l0 + 2];
    b3 += u * Dsh[j * 33 + l0 + 3];
  }
  ushort4v o;
  o[0] = f2bf(b0); o[1] = f2bf(b1); o[2] = f2bf(b2); o[3] = f2bf(b3);
  *(ushort4v*)(dst + k * 32 + l0) = o;
}

// ---- stage1: prep(0..2047) + weff 2-col (2048..2559) + beff(2560) + tok2(2561..2688)
// LDS = 8448 floats (33 KB) -> 4 blocks/CU for the memory-bound prep blocks.
__global__ __launch_bounds__(256) void k_stage1(const float* __restrict__ feats,
                                                const float* __restrict__ lt, const int* __restrict__ layerp,
                                                const float* __restrict__ Wt2f,
                                                const float* __restrict__ Wdf, const float* __restrict__ bdf,
                                                u16* __restrict__ xb, u16* __restrict__ wt_bf,
                                                u16* __restrict__ tok_bf, u16* __restrict__ A2,
                                                float* __restrict__ outp,
                                                float* __restrict__ weff_f, u16* __restrict__ weff_bf,
                                                float* __restrict__ beff, u16* __restrict__ tok2) {
  __shared__ __align__(16) float sm[8448];
  int bid = blockIdx.x, t = threadIdx.x;
  if (bid < 2048) {
    int tid = bid * 256 + t;   // 524288 total
    int L = *layerp;
    const float4* in4 = (const float4*)(feats + 32768);
    ushort4v* xb4 = (ushort4v*)xb;
    #pragma unroll
    for (int rep = 0; rep < 16; ++rep) {
      int j = tid + rep * 524288;
      float4 v = in4[j];
      ushort4v o;
      o[0] = f2bf(v.x); o[1] = f2bf(v.y); o[2] = f2bf(v.z); o[3] = f2bf(v.w);
      xb4[j] = o;
    }
    ((ushort8*)A2)[tid] = (ushort8){0,0,0,0,0,0,0,0};
    if (tid < 262144) {
      float4 v = ((const float4*)Wt2f)[tid];
      ushort4v o;
      o[0] = f2bf(v.x); o[1] = f2bf(v.y); o[2] = f2bf(v.z); o[3] = f2bf(v.w);
      ((ushort4v*)wt_bf)[tid] = o;
    }
    if (tid < 32768) {
      outp[tid] = feats[tid];
      int m = tid >> 8;
      ushort4v o = (ushort4v){0,0,0,0};
      if (m < 99) {
        float4 v = *(const float4*)(lt + (size_t)L * 102400 + (size_t)(m + 1) * 1024 + (tid & 255) * 4);
        o[0] = f2bf(v.x); o[1] = f2bf(v.y); o[2] = f2bf(v.z); o[3] = f2bf(v.w);
      }
      ((ushort4v*)tok_bf)[tid] = o;
    }
    return;
  }
  int b2 = bid - 2048;
  if (b2 < 512) {
    // weff = L @ W_df, 2 columns per block
    float* In = sm;            // 2*1056
    float* Uc = sm + 2112;     // 2*1056
    float* Us = sm + 4224;     // 2*1056
    float* Csh = sm + 6336;    // 1056
    float* Ssh = sm + 7392;    // 1056
    int c0 = b2 * 2;
    for (int i = t; i < 1024; i += 256) {
      int r = i >> 5, c = i & 31;
      float ang = (float)((r * c) & 31) * (PI_F / 16.0f);
      Csh[r * 33 + c] = cosf(ang); Ssh[r * 33 + c] = sinf(ang);
    }
    { int cc = t & 1, v0 = t >> 1;
      for (int v = v0; v < 1024; v += 128)
        In[cc * 1056 + (v >> 5) * 33 + (v & 31)] = Wdf[(size_t)v * 1024 + c0 + cc]; }
    __syncthreads();
    int cc = t >> 7, L7 = t & 127, p = L7 & 31, h = L7 >> 5;   // h in 0..3
    for (int j = h * 8; j < h * 8 + 8; ++j) {
      float ac = 0, as = 0;
      #pragma unroll 8
      for (int i = 0; i < 32; ++i) {
        float m = In[cc * 1056 + i * 33 + j];
        ac += Csh[p * 33 + i] * m;
        as += Ssh[p * 33 + i] * m;
      }
      Uc[cc * 1056 + p * 33 + j] = ac;
      Us[cc * 1056 + p * 33 + j] = as;
    }
    __syncthreads();
    for (int q = h * 8; q < h * 8 + 8; ++q) {
      float acc = 0;
      #pragma unroll 8
      for (int j = 0; j < 32; ++j)
        acc += Uc[cc * 1056 + p * 33 + j] * Csh[q * 33 + j] -
               Us[cc * 1056 + p * 33 + j] * Ssh[q * 33 + j];
      float val = acc * 0.03125f;
      size_t idx = (size_t)(p * 32 + q) * 1024 + c0 + cc;
      weff_f[idx] = val;
      weff_bf[idx] = f2bf(val);
    }
  } else if (b2 == 512) {
    float* Bsh = sm; float* Uc = sm + 1056; float* Us = sm + 2112;
    float* Csh = sm + 3168; float* Ssh = sm + 4224;
    for (int i = t; i < 1024; i += 256) {
      int r = i >> 5, c = i & 31;
      float ang = (float)((r * c) & 31) * (PI_F / 16.0f);
      Csh[r * 33 + c] = cosf(ang); Ssh[r * 33 + c] = sinf(ang);
      Bsh[r * 33 + c] = bdf[i];
    }
    __syncthreads();
    for (int idx = t; idx < 1024; idx += 256) {
      int p = idx >> 5, j = idx & 31;
      float ac = 0, as = 0;
      #pragma unroll 8
      for (int i = 0; i < 32; ++i) {
        float m = Bsh[i * 33 + j];
        ac += Csh[p * 33 + i] * m;
        as += Ssh[p * 33 + i] * m;
      }
      Uc[p * 33 + j] = ac; Us[p * 33 + j] = as;
    }
    __syncthreads();
    for (int idx = t; idx < 1024; idx += 256) {
      int p = idx >> 5, q = idx & 31;
      float acc = 0;
      #pragma unroll 8
      for (int jj = 0; jj < 32; ++jj)
        acc += Uc[p * 33 + jj] * Csh[q * 33 + jj] - Us[p * 33 + jj] * Ssh[q * 33 + jj];
      beff[idx] = acc * 0.03125f;
    }
  } else {
    int p = b2 - 513;   // 0..127
    if (p >= 100) {
      *(ushort4v*)(tok2 + (size_t)p * 1024 + t * 4) = (ushort4v){0,0,0,0};
      return;
    }
    mdct_row(lt + (size_t)(*layerp) * 102400 + (size_t)p * 1024, tok2 + (size_t)p * 1024, sm, t);
  }
}

// ---------------- 128x128 ring-buffer GEMM core (NT K-tiles of 32), counted vmcnt ------
template <int NT>
__device__ __forceinline__ void gemm128_core(const u16* __restrict__ A, int lda,
                                             const u16* __restrict__ B, int ldb,
                                             int g0, int c0, u16* smem,
                                             f32x4 (&acc)[4][4], int wid, int lane) {
  int wr = wid >> 1, wc = wid & 1, cl = lane & 15, rg = lane >> 4;
  stage_tile(A, lda, g0, 0, smem, wid, lane);
  stage_tile(B, ldb, c0, 0, smem + 12288, wid, lane);
  stage_tile(A, lda, g0, 32, smem + 4096, wid, lane);
  stage_tile(B, ldb, c0, 32, smem + 16384, wid, lane);
  int cur = 0;
  #pragma unroll 1
  for (int kt = 0; kt < NT; ++kt) {
    if (kt == NT - 1) { WAIT_VM(0); } else { WAIT_VM(4); }
    RAW_BARRIER();
    if (kt + 2 < NT) {
      int slot = (cur == 0) ? 2 : cur - 1;
      stage_tile(A, lda, g0, (kt + 2) * 32, smem + slot * 4096, wid, lane);
      stage_tile(B, ldb, c0, (kt + 2) * 32, smem + 12288 + slot * 4096, wid, lane);
    }
    const u16* pa = smem + cur * 4096;
    const u16* pb = smem + 12288 + cur * 4096;
    bf16x8 af[4], bv[4];
    #pragma unroll
    for (int mf = 0; mf < 4; mf++)
      af[mf] = *(const bf16x8*)(pa + (wr * 64 + mf * 16 + cl) * 32 + rg * 8);
    #pragma unroll
    for (int nf = 0; nf < 4; nf++)
      bv[nf] = *(const bf16x8*)(pb + (wc * 64 + nf * 16 + cl) * 32 + rg * 8);
    #pragma unroll
    for (int mf = 0; mf < 4; mf++)
      #pragma unroll
      for (int nf = 0; nf < 4; nf++)
        acc[mf][nf] = __builtin_amdgcn_mfma_f32_16x16x32_bf16(af[mf], bv[nf], acc[mf][nf], 0, 0, 0);
    cur = (cur == 2) ? 0 : cur + 1;
  }
}

// ---------------- stage2: w2 mdct (0..1023) + t2f GEMM (1024..1031) + attn (1032..1287) --
__global__ __launch_bounds__(256) void k_stage2(const float* __restrict__ weff_f,
                                                const u16* __restrict__ tok_bf, const u16* __restrict__ wt_bf,
                                                const float* __restrict__ bt2f,
                                                const u16* __restrict__ xb, const u16* __restrict__ tok2,
                                                u16* __restrict__ w2, u16* __restrict__ t2f,
                                                u16* __restrict__ A2) {
  __shared__ __align__(16) u16 smem[24576];
  int bid = blockIdx.x, t = threadIdx.x;
  int lane = t & 63, wid = t >> 6;
  if (bid < 1024) {
    mdct_row(weff_f + (size_t)bid * 1024, w2 + (size_t)bid * 1024, (float*)smem, t);
  } else if (bid < 1032) {
    int bn = bid - 1024;
    int wr = wid >> 1, wc = wid & 1, cl = lane & 15, rg = lane >> 4;
    f32x4 acc[4][4];
    #pragma unroll
    for (int i = 0; i < 4; i++)
      #pragma unroll
      for (int j = 0; j < 4; j++) acc[i][j] = (f32x4){0.f,0.f,0.f,0.f};
    gemm128_core<32>(tok_bf, 1024, wt_bf, 1024, 0, bn * 128, smem, acc, wid, lane);
    #pragma unroll
    for (int mf = 0; mf < 4; mf++)
      #pragma unroll
      for (int nf = 0; nf < 4; nf++) {
        int col = bn * 128 + wc * 64 + nf * 16 + cl;
        #pragma unroll
        for (int r = 0; r < 4; r++) {
          int row = wr * 64 + mf * 16 + rg * 4 + r;
          t2f[(size_t)row * 1024 + col] = (row < 99) ? f2bf(acc[mf][nf][r] + bt2f[col]) : (u16)0;
        }
      }
  } else {
    int g0 = (bid - 1032) * 128;
    int cl = lane & 15, rg = lane >> 4;
    f32x4 acc[2][7];
    #pragma unroll
    for (int i = 0; i < 2; i++)
      #pragma unroll
      for (int j = 0; j < 7; j++) acc[i][j] = (f32x4){0.f,0.f,0.f,0.f};
    stage_tile(xb, 1024, g0, 0, smem, wid, lane);
    stage_tile(tok2, 1024, 0, 0, smem + 12288, wid, lane);
    stage_tile(xb, 1024, g0, 32, smem + 4096, wid, lane);
    stage_tile(tok2, 1024, 0, 32, smem + 16384, wid, lane);
    int cur = 0;
    #pragma unroll 1
    for (int kt = 0; kt < 32; ++kt) {
      if (kt == 31) { WAIT_VM(0); } else { WAIT_VM(4); }
      RAW_BARRIER();
      if (kt + 2 < 32) {
        int slot = (cur == 0) ? 2 : cur - 1;
        stage_tile(xb, 1024, g0, (kt + 2) * 32, smem + slot * 4096, wid, lane);
        stage_tile(tok2, 1024, 0, (kt + 2) * 32, smem + 12288 + slot * 4096, wid, lane);
      }
      const u16* pa = smem + cur * 4096;
      const u16* pb = smem + 12288 + cur * 4096;
      bf16x8 a0 = *(const bf16x8*)(pa + (wid * 32 + cl) * 32 + rg * 8);
      bf16x8 a1 = *(const bf16x8*)(pa + (wid * 32 + 16 + cl) * 32 + rg * 8);
      #pragma unroll
      for (int nf = 0; nf < 7; nf++) {
        bf16x8 bv = *(const bf16x8*)(pb + (nf * 16 + cl) * 32 + rg * 8);
        acc[0][nf] = __builtin_amdgcn_mfma_f32_16x16x32_bf16(a0, bv, acc[0][nf], 0, 0, 0);
        acc[1][nf] = __builtin_amdgcn_mfma_f32_16x16x32_bf16(a1, bv, acc[1][nf], 0, 0, 0);
      }
      cur = (cur == 2) ? 0 : cur + 1;
    }
    #pragma unroll
    for (int mf = 0; mf < 2; mf++) {
      #pragma unroll
      for (int r = 0; r < 4; r++) {
        int grow = g0 + wid * 32 + mf * 16 + rg * 4 + r;
        float v[7];
        float mx = -1e30f;
        #pragma unroll
        for (int nf = 0; nf < 7; nf++) {
          int m = nf * 16 + cl;
          v[nf] = acc[mf][nf][r] * 0.03125f;
          if (m < 100) mx = fmaxf(mx, v[nf]);
        }
        #pragma unroll
        for (int d = 1; d < 16; d <<= 1) mx = fmaxf(mx, __shfl_xor(mx, d));
        float s = 0;
        #pragma unroll
        for (int nf = 0; nf < 7; nf++) {
          int m = nf * 16 + cl;
          float e = (m < 100) ? __expf(v[nf] - mx) : 0.0f;
          v[nf] = e; s += e;
        }
        #pragma unroll
        for (int d = 1; d < 16; d <<= 1) s += __shfl_xor(s, d);
        float inv = 1.0f / s;
        #pragma unroll
        for (int nf = 0; nf < 7; nf++) {
          int m = nf * 16 + cl;
          if (m >= 1 && m < 100) A2[(size_t)grow * 128 + (m - 1)] = f2bf(v[nf] * inv);
        }
      }
    }
  }
}

// ---------------- Gt GEMM (8 blocks): Gt = weff @ t2f^T ----------------
__global__ __launch_bounds__(256) void k_gt(const u16* __restrict__ weff_bf, const u16* __restrict__ t2f,
                                            u16* __restrict__ Gt) {
  __shared__ __align__(16) u16 smem[24576];
  int bid = blockIdx.x, t = threadIdx.x;
  int lane = t & 63, wid = t >> 6;
  int wr = wid >> 1, wc = wid & 1, cl = lane & 15, rg = lane >> 4;
  f32x4 acc[4][4];
  #pragma unroll
  for (int i = 0; i < 4; i++)
    #pragma unroll
    for (int j = 0; j < 4; j++) acc[i][j] = (f32x4){0.f,0.f,0.f,0.f};
  gemm128_core<32>(weff_bf, 1024, t2f, 1024, bid * 128, 0, smem, acc, wid, lane);
  #pragma unroll
  for (int mf = 0; mf < 4; mf++)
    #pragma unroll
    for (int nf = 0; nf < 4; nf++) {
      int col = wc * 64 + nf * 16 + cl;
      #pragma unroll
      for (int r = 0; r < 4; r++) {
        int row = bid * 128 + wr * 64 + mf * 16 + rg * 4 + r;
        Gt[(size_t)row * 128 + col] = f2bf(acc[mf][nf][r]);
      }
    }
}

// ---------------- main fused GEMM, 256x256 tile, 8 waves, BK=32, 2-slot dbuf (64 KB LDS,
// 2 blocks/CU -> cross-block latency hiding). out = x + clip([xb|A2]@[w2|Gt]^T + beff)*scale
__global__ __launch_bounds__(512, 2) void k_main(const u16* __restrict__ xb, const u16* __restrict__ w2,
                                                 const u16* __restrict__ a2, const u16* __restrict__ gt,
                                                 const float* __restrict__ beff, const float* __restrict__ feats,
                                                 const float* __restrict__ scalep, float* __restrict__ outf) {
  __shared__ __align__(16) u16 smem[32768];   // 64 KB: A slots 0/8192, B slots 16384/24576
  int tid = threadIdx.x, lane = tid & 63, wid = tid >> 6;
  int wr = wid >> 2, wc = wid & 3;            // 2 x 4 wave grid; wave tile 128x64
  int cl = lane & 15, rg = lane >> 4;
  int bid = blockIdx.x;
  int swz = (bid & 7) * 64 + (bid >> 3);      // XCD-chunked bijective swizzle (512 = 8*64)
  int bm = swz >> 2, bn = swz & 3;
  int g0 = bm * 256, c0 = bn * 256;

  f32x4 acc[8][4];
  #pragma unroll
  for (int i = 0; i < 8; i++)
    #pragma unroll
    for (int j = 0; j < 4; j++) acc[i][j] = (f32x4){0.f,0.f,0.f,0.f};

  const int NT = 36;   // K = 1152 = 36 x 32

  // precomputed swizzled fragment offsets (u16 units), statically indexed
  int offA[8], offB[4];
  #pragma unroll
  for (int mf = 0; mf < 8; ++mf) {
    int r = wr * 128 + mf * 16 + cl;
    int lrow = r >> 1;
    offA[mf] = lrow * 64 + (((((r & 1) << 2) | rg) ^ (lrow & 7)) << 3);
  }
  #pragma unroll
  for (int nf = 0; nf < 4; ++nf) {
    int r = wc * 64 + nf * 16 + cl;
    int lrow = r >> 1;
    offB[nf] = lrow * 64 + (((((r & 1) << 2) | rg) ^ (lrow & 7)) << 3);
  }

  auto issueA = [&](int t) {
    u16* R = smem + (t & 1) * 8192;
    const u16* G = (t < 32) ? xb : a2;
    int ld = (t < 32) ? 1024 : 128;
    int k0 = (t < 32) ? t * 32 : (t - 32) * 32;
    #pragma unroll
    for (int p = 0; p < 2; ++p) {
      int lrow = p * 64 + wid * 8 + (lane >> 3);
      int c2 = (lane & 7) ^ (lrow & 7);
      const u16* src = G + (size_t)(g0 + 2 * lrow + (c2 >> 2)) * ld + k0 + (c2 & 3) * 8;
      gload16(src, R + (p * 64 + wid * 8) * 64);
    }
  };
  auto issueB = [&](int t) {
    u16* R = smem + 16384 + (t & 1) * 8192;
    const u16* G = (t < 32) ? w2 : gt;
    int ld = (t < 32) ? 1024 : 128;
    int k0 = (t < 32) ? t * 32 : (t - 32) * 32;
    #pragma unroll
    for (int p = 0; p < 2; ++p) {
      int lrow = p * 64 + wid * 8 + (lane >> 3);
      int c2 = (lane & 7) ^ (lrow & 7);
      const u16* src = G + (size_t)(c0 + 2 * lrow + (c2 >> 2)) * ld + k0 + (c2 & 3) * 8;
      gload16(src, R + (p * 64 + wid * 8) * 64);
    }
  };

  issueA(0); issueB(0);   // prologue: 4 vm ops

  #pragma unroll 1
  for (int t = 0; t < NT; ++t) {
    WAIT_VM(0);            // tile-t loads landed (cross-block overlap hides this)
    RAW_BARRIER();
    if (t + 1 < NT) { issueA(t + 1); issueB(t + 1); }   // slot (t+1)&1: consumed at t-1
    int slot = t & 1;
    const u16* pa = smem + slot * 8192;
    const u16* pb = smem + 16384 + slot * 8192;
    bf16x8 af[8], bv[4];
    #pragma unroll
    for (int nf = 0; nf < 4; ++nf) bv[nf] = *(const bf16x8*)(pb + offB[nf]);
    #pragma unroll
    for (int mf = 0; mf < 8; ++mf) af[mf] = *(const bf16x8*)(pa + offA[mf]);
    __builtin_amdgcn_s_setprio(1);
    #pragma unroll
    for (int mf = 0; mf < 8; ++mf)
      #pragma unroll
      for (int nf = 0; nf < 4; ++nf)
        acc[mf][nf] = __builtin_amdgcn_mfma_f32_16x16x32_bf16(af[mf], bv[nf], acc[mf][nf], 0, 0, 0);
    __builtin_amdgcn_s_setprio(0);
  }

  float sc = *scalep;
  #pragma unroll
  for (int mf = 0; mf < 8; mf++) {
    #pragma unroll
    for (int nf = 0; nf < 4; nf++) {
      int col = c0 + wc * 64 + nf * 16 + cl;
      #pragma unroll
      for (int r = 0; r < 4; r++) {
        int row = g0 + wr * 128 + mf * 16 + rg * 4 + r;
        size_t idx = (size_t)row * 1024 + col;
        float val = acc[mf][nf][r] + beff[col];
        float rr = fminf(fmaxf(val, 0.f), 255.f);
        outf[32768 + idx] = feats[32768 + idx] + rr * sc;
      }
    }
  }
}

extern "C" void kernel_launch(void* const* d_in, const int* in_sizes, int n_in,
                              void* d_out, int out_size, void* d_ws, size_t ws_size,
                              hipStream_t stream) {
  const float* feats  = (const float*)d_in[0];
  const int*   layerp = (const int*)d_in[1];
  const float* lt     = (const float*)d_in[2];
  const float* scalep = (const float*)d_in[3];
  const float* Wt2f   = (const float*)d_in[4];
  const float* bt2f   = (const float*)d_in[5];
  const float* Wdf    = (const float*)d_in[6];
  const float* bdf    = (const float*)d_in[7];
  float* outp = (float*)d_out;

  char* ws = (char*)d_ws;
  float* beff   = (float*)(ws + 0);           // 4KB
  float* weff_f = (float*)(ws + 65536);       // 4MB
  u16* weff_bf = (u16*)(ws + 4259840);        // 2MB
  u16* w2      = (u16*)(ws + 6356992);        // 2MB
  u16* tok_bf  = (u16*)(ws + 8454144);        // 256KB
  u16* wt_bf   = (u16*)(ws + 8716288);        // 2MB
  u16* tok2    = (u16*)(ws + 10813440);       // 256KB
  u16* t2f     = (u16*)(ws + 11075584);       // 256KB
  u16* Gt      = (u16*)(ws + 11337728);       // 256KB (1024x128)
  u16* A2      = (u16*)(ws + 11599872);       // 8MB (32768x128)
  u16* xb      = (u16*)(ws + 19988480);       // 64MB (32768x1024)

  k_stage1<<<2689, 256, 0, stream>>>(feats, lt, layerp, Wt2f, Wdf, bdf,
                                     xb, wt_bf, tok_bf, A2, outp, weff_f, weff_bf, beff, tok2);
  k_stage2<<<1288, 256, 0, stream>>>(weff_f, tok_bf, wt_bf, bt2f, xb, tok2, w2, t2f, A2);
  k_gt<<<8, 256, 0, stream>>>(weff_bf, t2f, Gt);
  k_main<<<512, 512, 0, stream>>>(xb, w2, A2, Gt, beff, feats, scalep, outp);
}